// Round 1
// baseline (733.021 us; speedup 1.0000x reference)
//
#include <hip/hip_runtime.h>
#include <math.h>

#define B_   2048
#define D_   512
#define H_   1024
#define NS   100
#define KTOP 51

#define TM 64
#define TN 64
#define BK 16
#define LDSP (TM + 4)   // pad to 68 floats: keeps 16B alignment AND breaks bank stride

// ---------------- eps mean over S axis (memory-bound, 419 MB) ----------------
__global__ __launch_bounds__(256) void eps_mean_kernel(const float4* __restrict__ eps,
                                                       float4* __restrict__ em) {
    const int i = blockIdx.x * 256 + threadIdx.x;      // 262144 threads, one float4 each
    const int slice = (B_ * D_) / 4;                    // 262144 float4 per sample
    float4 s = make_float4(0.f, 0.f, 0.f, 0.f);
    #pragma unroll 4
    for (int n = 0; n < NS; ++n) {
        float4 v = eps[(size_t)n * slice + i];
        s.x += v.x; s.y += v.y; s.z += v.z; s.w += v.w;
    }
    const float inv = 1.0f / NS;
    s.x *= inv; s.y *= inv; s.z *= inv; s.w *= inv;
    em[i] = s;
}

// ---------------- GEMM1: h = relu(batch · W1^T + b1) ----------------
// A: (M,K) row-major, W: (N,K) row-major (NT gemm — both K-contiguous)
__global__ __launch_bounds__(256) void gemm1_relu(const float* __restrict__ A,
                                                  const float* __restrict__ W,
                                                  const float* __restrict__ bias,
                                                  float* __restrict__ C,
                                                  int M, int N, int K) {
    __shared__ __align__(16) float As[BK][LDSP];
    __shared__ __align__(16) float Bs[BK][LDSP];
    const int tx = threadIdx.x & 15;
    const int ty = threadIdx.x >> 4;
    const int m0 = blockIdx.y * TM;
    const int n0 = blockIdx.x * TN;
    const int lrow = threadIdx.x >> 2;   // 0..63: tile row this thread stages
    const int lq   = threadIdx.x & 3;    // which float4 within the 16-wide k slab
    float acc[4][4] = {};
    for (int k0 = 0; k0 < K; k0 += BK) {
        float4 av = *(const float4*)(A + (size_t)(m0 + lrow) * K + k0 + lq * 4);
        float4 bv = *(const float4*)(W + (size_t)(n0 + lrow) * K + k0 + lq * 4);
        __syncthreads();
        As[lq*4+0][lrow] = av.x; As[lq*4+1][lrow] = av.y;
        As[lq*4+2][lrow] = av.z; As[lq*4+3][lrow] = av.w;
        Bs[lq*4+0][lrow] = bv.x; Bs[lq*4+1][lrow] = bv.y;
        Bs[lq*4+2][lrow] = bv.z; Bs[lq*4+3][lrow] = bv.w;
        __syncthreads();
        #pragma unroll
        for (int kk = 0; kk < BK; ++kk) {
            float4 a4 = *(const float4*)&As[kk][ty * 4];
            float4 b4 = *(const float4*)&Bs[kk][tx * 4];
            const float a[4] = {a4.x, a4.y, a4.z, a4.w};
            const float b[4] = {b4.x, b4.y, b4.z, b4.w};
            #pragma unroll
            for (int i = 0; i < 4; ++i)
                #pragma unroll
                for (int j = 0; j < 4; ++j)
                    acc[i][j] = fmaf(a[i], b[j], acc[i][j]);
        }
    }
    #pragma unroll
    for (int i = 0; i < 4; ++i) {
        float4 o;
        float* po = (float*)&o;
        #pragma unroll
        for (int j = 0; j < 4; ++j) {
            float v = acc[i][j] + bias[n0 + tx*4 + j];
            po[j] = v > 0.f ? v : 0.f;
        }
        *(float4*)(C + (size_t)(m0 + ty*4 + i) * N + n0 + tx*4) = o;
    }
}

// ---------------- GEMM2 fused: mu & log_var & op epilogue ----------------
__global__ __launch_bounds__(256) void gemm2_fused(const float* __restrict__ Hm,
                                                   const float* __restrict__ W21,
                                                   const float* __restrict__ W22,
                                                   const float* __restrict__ b21,
                                                   const float* __restrict__ b22,
                                                   const float* __restrict__ em,
                                                   const float* __restrict__ batch,
                                                   float* __restrict__ op,
                                                   int M, int N, int K) {
    __shared__ __align__(16) float As [BK][LDSP];
    __shared__ __align__(16) float B1s[BK][LDSP];
    __shared__ __align__(16) float B2s[BK][LDSP];
    const int tx = threadIdx.x & 15;
    const int ty = threadIdx.x >> 4;
    const int m0 = blockIdx.y * TM;
    const int n0 = blockIdx.x * TN;
    const int lrow = threadIdx.x >> 2;
    const int lq   = threadIdx.x & 3;
    float accm[4][4] = {};
    float accv[4][4] = {};
    for (int k0 = 0; k0 < K; k0 += BK) {
        float4 av  = *(const float4*)(Hm  + (size_t)(m0 + lrow) * K + k0 + lq * 4);
        float4 b1v = *(const float4*)(W21 + (size_t)(n0 + lrow) * K + k0 + lq * 4);
        float4 b2v = *(const float4*)(W22 + (size_t)(n0 + lrow) * K + k0 + lq * 4);
        __syncthreads();
        As [lq*4+0][lrow] = av.x;  As [lq*4+1][lrow] = av.y;
        As [lq*4+2][lrow] = av.z;  As [lq*4+3][lrow] = av.w;
        B1s[lq*4+0][lrow] = b1v.x; B1s[lq*4+1][lrow] = b1v.y;
        B1s[lq*4+2][lrow] = b1v.z; B1s[lq*4+3][lrow] = b1v.w;
        B2s[lq*4+0][lrow] = b2v.x; B2s[lq*4+1][lrow] = b2v.y;
        B2s[lq*4+2][lrow] = b2v.z; B2s[lq*4+3][lrow] = b2v.w;
        __syncthreads();
        #pragma unroll
        for (int kk = 0; kk < BK; ++kk) {
            float4 a4 = *(const float4*)&As [kk][ty * 4];
            float4 c4 = *(const float4*)&B1s[kk][tx * 4];
            float4 d4 = *(const float4*)&B2s[kk][tx * 4];
            const float a[4] = {a4.x, a4.y, a4.z, a4.w};
            const float c[4] = {c4.x, c4.y, c4.z, c4.w};
            const float d[4] = {d4.x, d4.y, d4.z, d4.w};
            #pragma unroll
            for (int i = 0; i < 4; ++i)
                #pragma unroll
                for (int j = 0; j < 4; ++j) {
                    accm[i][j] = fmaf(a[i], c[j], accm[i][j]);
                    accv[i][j] = fmaf(a[i], d[j], accv[i][j]);
                }
        }
        __syncthreads();
    }
    #pragma unroll
    for (int i = 0; i < 4; ++i) {
        const int row = m0 + ty*4 + i;
        float4 o;
        float* po = (float*)&o;
        #pragma unroll
        for (int j = 0; j < 4; ++j) {
            const int col = n0 + tx*4 + j;
            float mu = accm[i][j] + b21[col];
            float lv = accv[i][j] + b22[col];
            float e  = em[(size_t)row * N + col];
            float bt = batch[(size_t)row * N + col];
            float v  = mu + e * expf(0.5f * lv);
            po[j] = (bt != 0.f) ? v : 0.f;
        }
        *(float4*)(op + (size_t)row * N + n0 + tx*4) = o;
    }
}

// ---------------- per-row top-51 keep mask ----------------
// one wave per row; exact jax.lax.top_k tie semantics (lower index wins)
__global__ __launch_bounds__(64) void topk_kernel(const float* __restrict__ op,
                                                  float* __restrict__ out) {
    const int b = blockIdx.x;
    const int lane = threadIdx.x;
    const float* row = op + (size_t)b * D_;
    float v[8], w[8];
    #pragma unroll
    for (int j = 0; j < 8; ++j) { v[j] = row[lane + j * 64]; w[j] = v[j]; }
    int keep = 0;
    for (int it = 0; it < KTOP; ++it) {
        // local argmax (strict > keeps smallest j -> smallest d for ties)
        float bm = v[0]; int bj = 0;
        #pragma unroll
        for (int j = 1; j < 8; ++j) if (v[j] > bm) { bm = v[j]; bj = j; }
        float rv = bm;
        int   ri = bj * 64 + lane;   // global column index
        #pragma unroll
        for (int off = 32; off; off >>= 1) {
            float ov = __shfl_xor(rv, off, 64);
            int   oi = __shfl_xor(ri, off, 64);
            if (ov > rv || (ov == rv && oi < ri)) { rv = ov; ri = oi; }
        }
        if ((ri & 63) == lane) { v[ri >> 6] = -INFINITY; keep |= 1 << (ri >> 6); }
    }
    #pragma unroll
    for (int j = 0; j < 8; ++j)
        out[(size_t)b * D_ + lane + j * 64] = ((keep >> j) & 1) ? w[j] : 0.0f;
}

extern "C" void kernel_launch(void* const* d_in, const int* in_sizes, int n_in,
                              void* d_out, int out_size, void* d_ws, size_t ws_size,
                              hipStream_t stream) {
    const float* batch = (const float*)d_in[0];
    const float* W1    = (const float*)d_in[1];
    const float* b1    = (const float*)d_in[2];
    const float* W21   = (const float*)d_in[3];
    const float* b21   = (const float*)d_in[4];
    const float* W22   = (const float*)d_in[5];
    const float* b22   = (const float*)d_in[6];
    const float* eps   = (const float*)d_in[7];
    float* out = (float*)d_out;

    char* ws = (char*)d_ws;
    float* hbuf = (float*)ws;                                  // 2048*1024*4 = 8 MB
    float* em   = (float*)(ws + (size_t)8  * 1024 * 1024);     // 4 MB
    float* opb  = (float*)(ws + (size_t)12 * 1024 * 1024);     // 4 MB

    hipLaunchKernelGGL(eps_mean_kernel, dim3((B_ * D_ / 4) / 256), dim3(256), 0, stream,
                       (const float4*)eps, (float4*)em);
    hipLaunchKernelGGL(gemm1_relu, dim3(H_ / TN, B_ / TM), dim3(256), 0, stream,
                       batch, W1, b1, hbuf, B_, H_, D_);
    hipLaunchKernelGGL(gemm2_fused, dim3(D_ / TN, B_ / TM), dim3(256), 0, stream,
                       hbuf, W21, W22, b21, b22, em, batch, opb, B_, D_, H_);
    hipLaunchKernelGGL(topk_kernel, dim3(B_), dim3(64), 0, stream, opb, out);
}

// Round 2
// 638.223 us; speedup vs baseline: 1.1485x; 1.1485x over previous
//
#include <hip/hip_runtime.h>
#include <math.h>

#define B_   2048
#define D_   512
#define H_   1024
#define NS   100
#define KTOP 51
#define BD   (B_ * D_)          // 1048576
#define SPLITK 4
#define KSEG (H_ / SPLITK)      // 256

#define TM 64
#define TN 64
#define BK 32
#define LDSP (TM + 4)           // 68: 16B-aligned rows, broken pow2 bank stride

// ---------------- GEMM1: h = relu(batch . W1^T + b1)  M=2048 N=1024 K=512 ----------------
// grid (16, 32), 256 thr, 2 blocks/CU
__global__ __launch_bounds__(256) void gemm1_relu(const float* __restrict__ A,
                                                  const float* __restrict__ W,
                                                  const float* __restrict__ bias,
                                                  float* __restrict__ C) {
    __shared__ __align__(16) float As[BK][LDSP];
    __shared__ __align__(16) float Bs[BK][LDSP];
    const int tx = threadIdx.x & 15;
    const int ty = threadIdx.x >> 4;
    const int m0 = blockIdx.y * TM;
    const int n0 = blockIdx.x * TN;
    const int lrow = threadIdx.x >> 2;   // 0..63
    const int lq   = threadIdx.x & 3;    // float4 slot within 16-wide half-slab
    const int ks   = lq * 4;
    float acc[4][4] = {};
    const float* pa = A + (size_t)(m0 + lrow) * D_ + ks;
    const float* pb = W + (size_t)(n0 + lrow) * D_ + ks;
    for (int k0 = 0; k0 < D_; k0 += BK) {
        float4 a0 = *(const float4*)(pa + k0);
        float4 a1 = *(const float4*)(pa + k0 + 16);
        float4 b0 = *(const float4*)(pb + k0);
        float4 b1 = *(const float4*)(pb + k0 + 16);
        __syncthreads();
        As[ks+0][lrow]=a0.x; As[ks+1][lrow]=a0.y; As[ks+2][lrow]=a0.z; As[ks+3][lrow]=a0.w;
        As[16+ks+0][lrow]=a1.x; As[16+ks+1][lrow]=a1.y; As[16+ks+2][lrow]=a1.z; As[16+ks+3][lrow]=a1.w;
        Bs[ks+0][lrow]=b0.x; Bs[ks+1][lrow]=b0.y; Bs[ks+2][lrow]=b0.z; Bs[ks+3][lrow]=b0.w;
        Bs[16+ks+0][lrow]=b1.x; Bs[16+ks+1][lrow]=b1.y; Bs[16+ks+2][lrow]=b1.z; Bs[16+ks+3][lrow]=b1.w;
        __syncthreads();
        #pragma unroll
        for (int kk = 0; kk < BK; ++kk) {
            float4 a4 = *(const float4*)&As[kk][ty * 4];
            float4 b4 = *(const float4*)&Bs[kk][tx * 4];
            const float a[4] = {a4.x, a4.y, a4.z, a4.w};
            const float b[4] = {b4.x, b4.y, b4.z, b4.w};
            #pragma unroll
            for (int i = 0; i < 4; ++i)
                #pragma unroll
                for (int j = 0; j < 4; ++j)
                    acc[i][j] = fmaf(a[i], b[j], acc[i][j]);
        }
    }
    #pragma unroll
    for (int i = 0; i < 4; ++i) {
        float4 o;
        float* po = (float*)&o;
        #pragma unroll
        for (int j = 0; j < 4; ++j) {
            float v = acc[i][j] + bias[n0 + tx*4 + j];
            po[j] = v > 0.f ? v : 0.f;
        }
        *(float4*)(C + (size_t)(m0 + ty*4 + i) * H_ + n0 + tx*4) = o;
    }
}

// ---------------- fused: split-K dual-GEMM (mu,lv partials) + eps-mean ----------------
// grid 2048 1D: odd bids stream eps (BW-bound), even bids do one 64x64xK/4 tile (VALU-bound).
// Disjoint pipes overlap (MI355X co-schedules mem-waves and VALU-waves at max, not sum).
__global__ __launch_bounds__(256) void gemm2_eps(const float* __restrict__ Hm,
                                                 const float* __restrict__ W21,
                                                 const float* __restrict__ W22,
                                                 const float4* __restrict__ eps,
                                                 float* __restrict__ muP,
                                                 float* __restrict__ lvP,
                                                 float4* __restrict__ em) {
    __shared__ __align__(16) float As [BK][LDSP];
    __shared__ __align__(16) float B1s[BK][LDSP];
    __shared__ __align__(16) float B2s[BK][LDSP];
    const int bid = blockIdx.x;
    if (bid & 1) {
        // ---- eps mean over NS samples: 1024 blocks x 256 thr x one float4 ----
        const int i = (bid >> 1) * 256 + threadIdx.x;
        float4 s = make_float4(0.f, 0.f, 0.f, 0.f);
        #pragma unroll 4
        for (int n = 0; n < NS; ++n) {
            float4 v = eps[(size_t)n * (BD / 4) + i];
            s.x += v.x; s.y += v.y; s.z += v.z; s.w += v.w;
        }
        const float inv = 1.0f / NS;
        s.x *= inv; s.y *= inv; s.z *= inv; s.w *= inv;
        em[i] = s;
        return;
    }
    const int g  = bid >> 1;            // 0..1023
    const int n0 = (g & 7) * TN;
    const int m0 = ((g >> 3) & 31) * TM;
    const int p  = g >> 8;              // split-K piece 0..3
    const int tx = threadIdx.x & 15;
    const int ty = threadIdx.x >> 4;
    const int lrow = threadIdx.x >> 2;
    const int lq   = threadIdx.x & 3;
    const int ks   = lq * 4;
    float accm[4][4] = {};
    float accv[4][4] = {};
    const float* pa = Hm  + (size_t)(m0 + lrow) * H_ + ks;
    const float* pc = W21 + (size_t)(n0 + lrow) * H_ + ks;
    const float* pd = W22 + (size_t)(n0 + lrow) * H_ + ks;
    const int kend = p * KSEG + KSEG;
    for (int k0 = p * KSEG; k0 < kend; k0 += BK) {
        float4 a0 = *(const float4*)(pa + k0);
        float4 a1 = *(const float4*)(pa + k0 + 16);
        float4 c0 = *(const float4*)(pc + k0);
        float4 c1 = *(const float4*)(pc + k0 + 16);
        float4 d0 = *(const float4*)(pd + k0);
        float4 d1 = *(const float4*)(pd + k0 + 16);
        __syncthreads();
        As [ks+0][lrow]=a0.x; As [ks+1][lrow]=a0.y; As [ks+2][lrow]=a0.z; As [ks+3][lrow]=a0.w;
        As [16+ks+0][lrow]=a1.x; As [16+ks+1][lrow]=a1.y; As [16+ks+2][lrow]=a1.z; As [16+ks+3][lrow]=a1.w;
        B1s[ks+0][lrow]=c0.x; B1s[ks+1][lrow]=c0.y; B1s[ks+2][lrow]=c0.z; B1s[ks+3][lrow]=c0.w;
        B1s[16+ks+0][lrow]=c1.x; B1s[16+ks+1][lrow]=c1.y; B1s[16+ks+2][lrow]=c1.z; B1s[16+ks+3][lrow]=c1.w;
        B2s[ks+0][lrow]=d0.x; B2s[ks+1][lrow]=d0.y; B2s[ks+2][lrow]=d0.z; B2s[ks+3][lrow]=d0.w;
        B2s[16+ks+0][lrow]=d1.x; B2s[16+ks+1][lrow]=d1.y; B2s[16+ks+2][lrow]=d1.z; B2s[16+ks+3][lrow]=d1.w;
        __syncthreads();
        #pragma unroll
        for (int kk = 0; kk < BK; ++kk) {
            float4 a4 = *(const float4*)&As [kk][ty * 4];
            float4 c4 = *(const float4*)&B1s[kk][tx * 4];
            float4 d4 = *(const float4*)&B2s[kk][tx * 4];
            const float a[4] = {a4.x, a4.y, a4.z, a4.w};
            const float c[4] = {c4.x, c4.y, c4.z, c4.w};
            const float d[4] = {d4.x, d4.y, d4.z, d4.w};
            #pragma unroll
            for (int i = 0; i < 4; ++i)
                #pragma unroll
                for (int j = 0; j < 4; ++j) {
                    accm[i][j] = fmaf(a[i], c[j], accm[i][j]);
                    accv[i][j] = fmaf(a[i], d[j], accv[i][j]);
                }
        }
    }
    float* mb = muP + (size_t)p * BD;
    float* lb = lvP + (size_t)p * BD;
    #pragma unroll
    for (int i = 0; i < 4; ++i) {
        const size_t ro = (size_t)(m0 + ty*4 + i) * D_ + n0 + tx*4;
        float4 om, ol;
        om.x = accm[i][0]; om.y = accm[i][1]; om.z = accm[i][2]; om.w = accm[i][3];
        ol.x = accv[i][0]; ol.y = accv[i][1]; ol.z = accv[i][2]; ol.w = accv[i][3];
        *(float4*)(mb + ro) = om;
        *(float4*)(lb + ro) = ol;
    }
}

// ---------------- epilogue + per-row top-51 keep mask ----------------
// one wave per row; lane owns 8 contiguous cols. Exact jax tie semantics (lower index wins).
__global__ __launch_bounds__(64) void topk_fused(const float* __restrict__ muP,
                                                 const float* __restrict__ lvP,
                                                 const float* __restrict__ b21,
                                                 const float* __restrict__ b22,
                                                 const float* __restrict__ em,
                                                 const float* __restrict__ batch,
                                                 float* __restrict__ out) {
    const int b = blockIdx.x;
    const int lane = threadIdx.x;
    const int cbase = lane * 8;
    const size_t base = (size_t)b * D_ + cbase;

    float mu[8] = {}, lv[8] = {};
    #pragma unroll
    for (int p = 0; p < SPLITK; ++p) {
        const float* mp = muP + (size_t)p * BD + base;
        const float* lp = lvP + (size_t)p * BD + base;
        float4 a0 = *(const float4*)mp, a1 = *(const float4*)(mp + 4);
        float4 c0 = *(const float4*)lp, c1 = *(const float4*)(lp + 4);
        mu[0]+=a0.x; mu[1]+=a0.y; mu[2]+=a0.z; mu[3]+=a0.w;
        mu[4]+=a1.x; mu[5]+=a1.y; mu[6]+=a1.z; mu[7]+=a1.w;
        lv[0]+=c0.x; lv[1]+=c0.y; lv[2]+=c0.z; lv[3]+=c0.w;
        lv[4]+=c1.x; lv[5]+=c1.y; lv[6]+=c1.z; lv[7]+=c1.w;
    }
    float4 bm0 = *(const float4*)(b21 + cbase), bm1 = *(const float4*)(b21 + cbase + 4);
    float4 bl0 = *(const float4*)(b22 + cbase), bl1 = *(const float4*)(b22 + cbase + 4);
    float4 e0  = *(const float4*)(em + base),  e1  = *(const float4*)(em + base + 4);
    float4 t0  = *(const float4*)(batch + base), t1 = *(const float4*)(batch + base + 4);
    const float bmv[8] = {bm0.x,bm0.y,bm0.z,bm0.w,bm1.x,bm1.y,bm1.z,bm1.w};
    const float blv[8] = {bl0.x,bl0.y,bl0.z,bl0.w,bl1.x,bl1.y,bl1.z,bl1.w};
    const float ev[8]  = {e0.x,e0.y,e0.z,e0.w,e1.x,e1.y,e1.z,e1.w};
    const float tv[8]  = {t0.x,t0.y,t0.z,t0.w,t1.x,t1.y,t1.z,t1.w};

    float v[8], w[8];
    #pragma unroll
    for (int j = 0; j < 8; ++j) {
        float m = mu[j] + bmv[j];
        float l = lv[j] + blv[j];
        float val = m + ev[j] * expf(0.5f * l);
        val = (tv[j] != 0.f) ? val : 0.f;
        v[j] = val; w[j] = val;
    }
    int keep = 0;
    for (int it = 0; it < KTOP; ++it) {
        float bm = v[0]; int bj = 0;
        #pragma unroll
        for (int j = 1; j < 8; ++j) if (v[j] > bm) { bm = v[j]; bj = j; }   // strict >: lowest col wins ties
        float rv = bm;
        int   ri = cbase + bj;
        #pragma unroll
        for (int off = 32; off; off >>= 1) {
            float ov = __shfl_xor(rv, off, 64);
            int   oi = __shfl_xor(ri, off, 64);
            if (ov > rv || (ov == rv && oi < ri)) { rv = ov; ri = oi; }
        }
        if ((ri >> 3) == lane) { v[ri & 7] = -INFINITY; keep |= 1 << (ri & 7); }
    }
    float4 o0, o1;
    float* po = (float*)&o0;
    #pragma unroll
    for (int j = 0; j < 4; ++j) po[j] = ((keep >> j) & 1) ? w[j] : 0.0f;
    po = (float*)&o1;
    #pragma unroll
    for (int j = 0; j < 4; ++j) po[j] = ((keep >> (j+4)) & 1) ? w[j+4] : 0.0f;
    *(float4*)(out + base) = o0;
    *(float4*)(out + base + 4) = o1;
}

extern "C" void kernel_launch(void* const* d_in, const int* in_sizes, int n_in,
                              void* d_out, int out_size, void* d_ws, size_t ws_size,
                              hipStream_t stream) {
    const float* batch = (const float*)d_in[0];
    const float* W1    = (const float*)d_in[1];
    const float* b1    = (const float*)d_in[2];
    const float* W21   = (const float*)d_in[3];
    const float* b21   = (const float*)d_in[4];
    const float* W22   = (const float*)d_in[5];
    const float* b22   = (const float*)d_in[6];
    const float* eps   = (const float*)d_in[7];
    float* out = (float*)d_out;

    char* ws = (char*)d_ws;
    float* hbuf = (float*)ws;                                   // 8 MB  (2048x1024)
    float* em   = (float*)(ws + (size_t)8  * 1024 * 1024);      // 4 MB  (2048x512)
    float* muP  = (float*)(ws + (size_t)12 * 1024 * 1024);      // 16 MB (4 x 2048x512)
    float* lvP  = (float*)(ws + (size_t)28 * 1024 * 1024);      // 16 MB

    hipLaunchKernelGGL(gemm1_relu, dim3(H_ / TN, B_ / TM), dim3(256), 0, stream,
                       batch, W1, b1, hbuf);
    hipLaunchKernelGGL(gemm2_eps, dim3(2048), dim3(256), 0, stream,
                       hbuf, W21, W22, (const float4*)eps, muP, lvP, (float4*)em);
    hipLaunchKernelGGL(topk_fused, dim3(B_), dim3(64), 0, stream,
                       muP, lvP, b21, b22, em, batch, out);
}

// Round 3
// 626.978 us; speedup vs baseline: 1.1691x; 1.0179x over previous
//
#include <hip/hip_runtime.h>
#include <math.h>

#define B_   2048
#define D_   512
#define H_   1024
#define NS   100
#define KTOP 51
#define BD   (B_ * D_)          // 1048576
#define SPLITK 2

#define TM 64
#define TN 32
#define BK 32
#define LDA (TM + 4)            // 68 floats: 16B-aligned rows, broken pow2 stride
#define LDB (TN + 4)            // 36 floats

// ---- eps-mean worker: block e covers 256 consecutive float4 of em ----
__device__ __forceinline__ void eps_block(const float4* __restrict__ eps,
                                          float4* __restrict__ em, int e) {
    const int t = threadIdx.x;
    const int base = e * 256;
    float4 s0 = {0,0,0,0}, s1 = {0,0,0,0}, s2 = {0,0,0,0}, s3 = {0,0,0,0};
    #pragma unroll 2
    for (int n = 0; n < NS; ++n) {
        const float4* p = eps + (size_t)n * (BD / 4) + base + t;
        float4 v0 = p[0], v1 = p[64], v2 = p[128], v3 = p[192];
        s0.x+=v0.x; s0.y+=v0.y; s0.z+=v0.z; s0.w+=v0.w;
        s1.x+=v1.x; s1.y+=v1.y; s1.z+=v1.z; s1.w+=v1.w;
        s2.x+=v2.x; s2.y+=v2.y; s2.z+=v2.z; s2.w+=v2.w;
        s3.x+=v3.x; s3.y+=v3.y; s3.z+=v3.z; s3.w+=v3.w;
    }
    const float inv = 1.0f / NS;
    s0.x*=inv; s0.y*=inv; s0.z*=inv; s0.w*=inv;
    s1.x*=inv; s1.y*=inv; s1.z*=inv; s1.w*=inv;
    s2.x*=inv; s2.y*=inv; s2.z*=inv; s2.w*=inv;
    s3.x*=inv; s3.y*=inv; s3.z*=inv; s3.w*=inv;
    em[base + t]       = s0;
    em[base + t + 64]  = s1;
    em[base + t + 128] = s2;
    em[base + t + 192] = s3;
}

// ---------------- dispatch 1: gemm1 (h = relu(batch.W1^T + b1)) + 1/4 of eps ----------------
// grid 1280 x 64thr: bid%5==4 -> eps block (256 of them); else gemm tile (1024)
__global__ __launch_bounds__(64) void k1_gemm1_eps(const float* __restrict__ A,
                                                   const float* __restrict__ W,
                                                   const float* __restrict__ bias,
                                                   float* __restrict__ C,
                                                   const float4* __restrict__ eps,
                                                   float4* __restrict__ em) {
    __shared__ __align__(16) float As[BK][LDA];
    __shared__ __align__(16) float Bs[BK][LDB];
    const int r = blockIdx.x % 5, q = blockIdx.x / 5;
    if (r == 4) { eps_block(eps, em, q); return; }
    const int g  = q * 4 + r;            // 0..1023
    const int n0 = (g & 31) * TN;        // 32 n-tiles
    const int m0 = (g >> 5) * TM;        // 32 m-tiles
    const int t  = threadIdx.x;
    const int ri8 = (t >> 3) * 8;
    const int ci4 = (t & 7) * 4;
    const int bro = t >> 1;              // B stage: row within tile
    const int bko = (t & 1) * 16;        // B stage: k sub-slab
    float acc[8][4] = {};
    const float* pa = A + (size_t)(m0 + t) * D_;
    const float* pb = W + (size_t)(n0 + bro) * D_ + bko;
    for (int k0 = 0; k0 < D_; k0 += BK) {
        float4 av[8], bv[4];
        #pragma unroll
        for (int j = 0; j < 8; ++j) av[j] = *(const float4*)(pa + k0 + j * 4);
        #pragma unroll
        for (int j = 0; j < 4; ++j) bv[j] = *(const float4*)(pb + k0 + j * 4);
        __syncthreads();
        #pragma unroll
        for (int j = 0; j < 8; ++j) {
            As[j*4+0][t] = av[j].x; As[j*4+1][t] = av[j].y;
            As[j*4+2][t] = av[j].z; As[j*4+3][t] = av[j].w;
        }
        #pragma unroll
        for (int j = 0; j < 4; ++j) {
            Bs[bko+j*4+0][bro] = bv[j].x; Bs[bko+j*4+1][bro] = bv[j].y;
            Bs[bko+j*4+2][bro] = bv[j].z; Bs[bko+j*4+3][bro] = bv[j].w;
        }
        __syncthreads();
        #pragma unroll
        for (int kk = 0; kk < BK; ++kk) {
            float4 a0 = *(const float4*)&As[kk][ri8];
            float4 a1 = *(const float4*)&As[kk][ri8 + 4];
            float4 b0 = *(const float4*)&Bs[kk][ci4];
            const float a[8] = {a0.x,a0.y,a0.z,a0.w,a1.x,a1.y,a1.z,a1.w};
            const float b[4] = {b0.x,b0.y,b0.z,b0.w};
            #pragma unroll
            for (int i = 0; i < 8; ++i)
                #pragma unroll
                for (int j = 0; j < 4; ++j)
                    acc[i][j] = fmaf(a[i], b[j], acc[i][j]);
        }
    }
    float4 bb = *(const float4*)(bias + n0 + ci4);
    const float bv4[4] = {bb.x, bb.y, bb.z, bb.w};
    #pragma unroll
    for (int i = 0; i < 8; ++i) {
        float4 o; float* po = (float*)&o;
        #pragma unroll
        for (int j = 0; j < 4; ++j) {
            float v = acc[i][j] + bv4[j];
            po[j] = v > 0.f ? v : 0.f;
        }
        *(float4*)(C + (size_t)(m0 + ri8 + i) * H_ + n0 + ci4) = o;
    }
}

// ---------------- dispatch 2: dual-GEMM split-K (mu,lv partials) + 3/4 of eps ----------------
// grid 1792 x 64thr: bid%7<4 -> gemm tile (1024); else eps block (768, offset 256)
__global__ __launch_bounds__(64) void k2_gemm2_eps(const float* __restrict__ Hm,
                                                   const float* __restrict__ W21,
                                                   const float* __restrict__ W22,
                                                   float* __restrict__ muP,
                                                   float* __restrict__ lvP,
                                                   const float4* __restrict__ eps,
                                                   float4* __restrict__ em) {
    __shared__ __align__(16) float As[BK][LDA];
    __shared__ __align__(16) float Cs[BK][LDB];
    __shared__ __align__(16) float Ds[BK][LDB];
    const int r = blockIdx.x % 7, q = blockIdx.x / 7;
    if (r >= 4) { eps_block(eps, em, 256 + q * 3 + (r - 4)); return; }
    const int g  = q * 4 + r;              // 0..1023
    const int n0 = (g & 15) * TN;          // 16 n-tiles (D=512)
    const int m0 = ((g >> 4) & 31) * TM;   // 32 m-tiles
    const int p  = g >> 9;                 // split-K 0..1
    const int t  = threadIdx.x;
    const int ri8 = (t >> 3) * 8;
    const int ci4 = (t & 7) * 4;
    const int bro = t >> 1;
    const int bko = (t & 1) * 16;
    float accm[8][4] = {};
    float accv[8][4] = {};
    const int kbase = p * (H_ / SPLITK);   // 0 or 512
    const float* pa = Hm  + (size_t)(m0 + t) * H_ + kbase;
    const float* pc = W21 + (size_t)(n0 + bro) * H_ + kbase + bko;
    const float* pd = W22 + (size_t)(n0 + bro) * H_ + kbase + bko;
    for (int k0 = 0; k0 < H_ / SPLITK; k0 += BK) {
        float4 av[8], cv[4], dv[4];
        #pragma unroll
        for (int j = 0; j < 8; ++j) av[j] = *(const float4*)(pa + k0 + j * 4);
        #pragma unroll
        for (int j = 0; j < 4; ++j) cv[j] = *(const float4*)(pc + k0 + j * 4);
        #pragma unroll
        for (int j = 0; j < 4; ++j) dv[j] = *(const float4*)(pd + k0 + j * 4);
        __syncthreads();
        #pragma unroll
        for (int j = 0; j < 8; ++j) {
            As[j*4+0][t] = av[j].x; As[j*4+1][t] = av[j].y;
            As[j*4+2][t] = av[j].z; As[j*4+3][t] = av[j].w;
        }
        #pragma unroll
        for (int j = 0; j < 4; ++j) {
            Cs[bko+j*4+0][bro] = cv[j].x; Cs[bko+j*4+1][bro] = cv[j].y;
            Cs[bko+j*4+2][bro] = cv[j].z; Cs[bko+j*4+3][bro] = cv[j].w;
            Ds[bko+j*4+0][bro] = dv[j].x; Ds[bko+j*4+1][bro] = dv[j].y;
            Ds[bko+j*4+2][bro] = dv[j].z; Ds[bko+j*4+3][bro] = dv[j].w;
        }
        __syncthreads();
        #pragma unroll
        for (int kk = 0; kk < BK; ++kk) {
            float4 a0 = *(const float4*)&As[kk][ri8];
            float4 a1 = *(const float4*)&As[kk][ri8 + 4];
            float4 c0 = *(const float4*)&Cs[kk][ci4];
            float4 d0 = *(const float4*)&Ds[kk][ci4];
            const float a[8] = {a0.x,a0.y,a0.z,a0.w,a1.x,a1.y,a1.z,a1.w};
            const float c[4] = {c0.x,c0.y,c0.z,c0.w};
            const float d[4] = {d0.x,d0.y,d0.z,d0.w};
            #pragma unroll
            for (int i = 0; i < 8; ++i)
                #pragma unroll
                for (int j = 0; j < 4; ++j) {
                    accm[i][j] = fmaf(a[i], c[j], accm[i][j]);
                    accv[i][j] = fmaf(a[i], d[j], accv[i][j]);
                }
        }
    }
    float* mb = muP + (size_t)p * BD;
    float* lb = lvP + (size_t)p * BD;
    #pragma unroll
    for (int i = 0; i < 8; ++i) {
        const size_t ro = (size_t)(m0 + ri8 + i) * D_ + n0 + ci4;
        float4 om, ol;
        om.x = accm[i][0]; om.y = accm[i][1]; om.z = accm[i][2]; om.w = accm[i][3];
        ol.x = accv[i][0]; ol.y = accv[i][1]; ol.z = accv[i][2]; ol.w = accv[i][3];
        *(float4*)(mb + ro) = om;
        *(float4*)(lb + ro) = ol;
    }
}

// ---------------- epilogue + per-row top-51 keep mask ----------------
__global__ __launch_bounds__(64) void topk_fused(const float* __restrict__ muP,
                                                 const float* __restrict__ lvP,
                                                 const float* __restrict__ b21,
                                                 const float* __restrict__ b22,
                                                 const float* __restrict__ em,
                                                 const float* __restrict__ batch,
                                                 float* __restrict__ out) {
    const int b = blockIdx.x;
    const int lane = threadIdx.x;
    const int cbase = lane * 8;
    const size_t base = (size_t)b * D_ + cbase;

    float mu[8] = {}, lv[8] = {};
    #pragma unroll
    for (int p = 0; p < SPLITK; ++p) {
        const float* mp = muP + (size_t)p * BD + base;
        const float* lp = lvP + (size_t)p * BD + base;
        float4 a0 = *(const float4*)mp, a1 = *(const float4*)(mp + 4);
        float4 c0 = *(const float4*)lp, c1 = *(const float4*)(lp + 4);
        mu[0]+=a0.x; mu[1]+=a0.y; mu[2]+=a0.z; mu[3]+=a0.w;
        mu[4]+=a1.x; mu[5]+=a1.y; mu[6]+=a1.z; mu[7]+=a1.w;
        lv[0]+=c0.x; lv[1]+=c0.y; lv[2]+=c0.z; lv[3]+=c0.w;
        lv[4]+=c1.x; lv[5]+=c1.y; lv[6]+=c1.z; lv[7]+=c1.w;
    }
    float4 bm0 = *(const float4*)(b21 + cbase), bm1 = *(const float4*)(b21 + cbase + 4);
    float4 bl0 = *(const float4*)(b22 + cbase), bl1 = *(const float4*)(b22 + cbase + 4);
    float4 e0  = *(const float4*)(em + base),  e1  = *(const float4*)(em + base + 4);
    float4 t0  = *(const float4*)(batch + base), t1 = *(const float4*)(batch + base + 4);
    const float bmv[8] = {bm0.x,bm0.y,bm0.z,bm0.w,bm1.x,bm1.y,bm1.z,bm1.w};
    const float blv[8] = {bl0.x,bl0.y,bl0.z,bl0.w,bl1.x,bl1.y,bl1.z,bl1.w};
    const float ev[8]  = {e0.x,e0.y,e0.z,e0.w,e1.x,e1.y,e1.z,e1.w};
    const float tv[8]  = {t0.x,t0.y,t0.z,t0.w,t1.x,t1.y,t1.z,t1.w};

    float v[8], w[8];
    #pragma unroll
    for (int j = 0; j < 8; ++j) {
        float m = mu[j] + bmv[j];
        float l = lv[j] + blv[j];
        float val = m + ev[j] * expf(0.5f * l);
        val = (tv[j] != 0.f) ? val : 0.f;
        v[j] = val; w[j] = val;
    }
    int keep = 0;
    for (int it = 0; it < KTOP; ++it) {
        float bm = v[0]; int bj = 0;
        #pragma unroll
        for (int j = 1; j < 8; ++j) if (v[j] > bm) { bm = v[j]; bj = j; }   // strict >: lowest col wins ties
        float rv = bm;
        int   ri = cbase + bj;
        #pragma unroll
        for (int off = 32; off; off >>= 1) {
            float ov = __shfl_xor(rv, off, 64);
            int   oi = __shfl_xor(ri, off, 64);
            if (ov > rv || (ov == rv && oi < ri)) { rv = ov; ri = oi; }
        }
        if ((ri >> 3) == lane) { v[ri & 7] = -INFINITY; keep |= 1 << (ri & 7); }
    }
    float4 o0, o1;
    float* po = (float*)&o0;
    #pragma unroll
    for (int j = 0; j < 4; ++j) po[j] = ((keep >> j) & 1) ? w[j] : 0.0f;
    po = (float*)&o1;
    #pragma unroll
    for (int j = 0; j < 4; ++j) po[j] = ((keep >> (j+4)) & 1) ? w[j+4] : 0.0f;
    *(float4*)(out + base) = o0;
    *(float4*)(out + base + 4) = o1;
}

extern "C" void kernel_launch(void* const* d_in, const int* in_sizes, int n_in,
                              void* d_out, int out_size, void* d_ws, size_t ws_size,
                              hipStream_t stream) {
    const float* batch = (const float*)d_in[0];
    const float* W1    = (const float*)d_in[1];
    const float* b1    = (const float*)d_in[2];
    const float* W21   = (const float*)d_in[3];
    const float* b21   = (const float*)d_in[4];
    const float* W22   = (const float*)d_in[5];
    const float* b22   = (const float*)d_in[6];
    const float* eps   = (const float*)d_in[7];
    float* out = (float*)d_out;

    char* ws = (char*)d_ws;
    float* hbuf = (float*)ws;                                   // 8 MB  (2048x1024)
    float* em   = (float*)(ws + (size_t)8  * 1024 * 1024);      // 4 MB  (2048x512)
    float* muP  = (float*)(ws + (size_t)12 * 1024 * 1024);      // 8 MB  (2 x 2048x512)
    float* lvP  = (float*)(ws + (size_t)20 * 1024 * 1024);      // 8 MB

    hipLaunchKernelGGL(k1_gemm1_eps, dim3(1280), dim3(64), 0, stream,
                       batch, W1, b1, hbuf, (const float4*)eps, (float4*)em);
    hipLaunchKernelGGL(k2_gemm2_eps, dim3(1792), dim3(64), 0, stream,
                       hbuf, W21, W22, muP, lvP, (const float4*)eps, (float4*)em);
    hipLaunchKernelGGL(topk_fused, dim3(B_), dim3(64), 0, stream,
                       muP, lvP, b21, b22, em, batch, out);
}